// Round 2
// baseline (162.615 us; speedup 1.0000x reference)
//
#include <hip/hip_runtime.h>
#include <stdint.h>

typedef __attribute__((ext_vector_type(8))) short short8v;   // 8 x bf16 (4 VGPR)
typedef __attribute__((ext_vector_type(4))) float f32x4;     // mfma accumulator

__device__ __forceinline__ unsigned short f2bf(float f) {
  union { float f; unsigned int i; } v; v.f = f;
  unsigned int x = v.i;
  x += 0x7FFFu + ((x >> 16) & 1u);   // round-to-nearest-even
  return (unsigned short)(x >> 16);
}

// ---------------------------------------------------------------------------
// K1: build scaled padded reflector vectors in fp32:
//     vfull[k][c] = (c >= 254-k) ? V[k][c] : 1.0
//     Vs[k][c]    = sqrt(2 / (||vfull||^2 + 1e-16)) * vfull[k][c]
// so the cascade step is simply q -= (q . vs) * vs
// ---------------------------------------------------------------------------
__global__ void __launch_bounds__(256) prep_kernel(const float* __restrict__ V,
                                                   float* __restrict__ Vs) {
  const int k = blockIdx.x;      // 0..254
  const int c = threadIdx.x;     // 0..255
  float val = (c >= 254 - k) ? V[k * 256 + c] : 1.0f;
  float ss = val * val;
  #pragma unroll
  for (int off = 32; off >= 1; off >>= 1) ss += __shfl_xor(ss, off);
  __shared__ float part[4];
  if ((threadIdx.x & 63) == 0) part[threadIdx.x >> 6] = ss;
  __syncthreads();
  const float tot = part[0] + part[1] + part[2] + part[3];
  const float s = sqrtf(2.0f / (tot + 1e-16f));
  Vs[k * 256 + c] = s * val;
}

// ---------------------------------------------------------------------------
// K2: Householder cascade. Q row r evolves independently (right-multiplication
// by each reflector): q <- q - (q . vs_k) vs_k , k = 0..254.
// 4 rows per wave (independent reduce chains -> ILP hides shfl latency).
// Lane l owns columns 4l..4l+3. Output: W as bf16, row-major [o][c].
// ---------------------------------------------------------------------------
__global__ void __launch_bounds__(256) cascade_kernel(const float* __restrict__ Vs,
                                                      unsigned short* __restrict__ Wb) {
  const int w = threadIdx.x >> 6;            // wave in block: 0..3
  const int l = threadIdx.x & 63;            // lane
  const int r0 = blockIdx.x * 16 + w * 4;    // first of 4 rows for this wave

  f32x4 q[4];
  #pragma unroll
  for (int j = 0; j < 4; ++j) {
    const int r = r0 + j;
    q[j][0] = (4 * l + 0 == r) ? 1.0f : 0.0f;
    q[j][1] = (4 * l + 1 == r) ? 1.0f : 0.0f;
    q[j][2] = (4 * l + 2 == r) ? 1.0f : 0.0f;
    q[j][3] = (4 * l + 3 == r) ? 1.0f : 0.0f;
  }

  const f32x4* __restrict__ Vs4 = (const f32x4*)Vs;   // [255][64] float4
  f32x4 vn = Vs4[l];
  for (int k = 0; k < 255; ++k) {
    const f32x4 v = vn;
    if (k + 1 < 255) vn = Vs4[(k + 1) * 64 + l];
    float p[4];
    #pragma unroll
    for (int j = 0; j < 4; ++j)
      p[j] = q[j][0] * v[0] + q[j][1] * v[1] + q[j][2] * v[2] + q[j][3] * v[3];
    #pragma unroll
    for (int off = 32; off >= 1; off >>= 1) {
      #pragma unroll
      for (int j = 0; j < 4; ++j) p[j] += __shfl_xor(p[j], off);
    }
    #pragma unroll
    for (int j = 0; j < 4; ++j) {
      q[j][0] -= p[j] * v[0];
      q[j][1] -= p[j] * v[1];
      q[j][2] -= p[j] * v[2];
      q[j][3] -= p[j] * v[3];
    }
  }

  #pragma unroll
  for (int j = 0; j < 4; ++j) {
    ushort4 o;
    o.x = f2bf(q[j][0]); o.y = f2bf(q[j][1]); o.z = f2bf(q[j][2]); o.w = f2bf(q[j][3]);
    *(ushort4*)(Wb + (size_t)(r0 + j) * 256 + 4 * l) = o;
  }
}

// ---------------------------------------------------------------------------
// K3: y[b][o][n] = sum_c W[o][c] x[b][c][n]   (M=256, K=256, N=4096 per batch)
// 4 waves; wave w computes rows 64w..64w+63; block covers an n-tile of 64.
// A: 16B bf16 loads from L2-resident W. B: per-lane stride-4096 fp32 dword
// gathers (16 lanes = 64B contiguous segments), converted to bf16 on the fly.
// mfma_f32_16x16x32_bf16, fp32 accumulate, fp32 stores.
// ---------------------------------------------------------------------------
__global__ void __launch_bounds__(256) conv_kernel(const float* __restrict__ x,
                                                   const unsigned short* __restrict__ Wb,
                                                   float* __restrict__ y) {
  const int b  = blockIdx.y;
  const int n0 = blockIdx.x * 64;
  const int w  = threadIdx.x >> 6;     // wave -> M block (64 rows)
  const int l  = threadIdx.x & 63;
  const int lr = l & 15;               // row/col within fragment
  const int lg = l >> 4;               // k-group

  const float* __restrict__ xb = x + (size_t)b * (256u * 4096u);
  float* __restrict__ yb = y + (size_t)b * (256u * 4096u);

  f32x4 acc[4][4];
  #pragma unroll
  for (int i = 0; i < 4; ++i)
    #pragma unroll
    for (int j = 0; j < 4; ++j)
      acc[i][j] = (f32x4){0.f, 0.f, 0.f, 0.f};

  for (int k0 = 0; k0 < 256; k0 += 32) {
    short8v a[4];
    #pragma unroll
    for (int i = 0; i < 4; ++i)
      a[i] = *(const short8v*)(Wb + (size_t)(64 * w + 16 * i + lr) * 256 + k0 + 8 * lg);

    short8v bb[4];
    #pragma unroll
    for (int jn = 0; jn < 4; ++jn) {
      const float* __restrict__ bp =
          xb + (size_t)(k0 + 8 * lg) * 4096 + n0 + 16 * jn + lr;
      short8v t;
      #pragma unroll
      for (int j = 0; j < 8; ++j) t[j] = (short)f2bf(bp[(size_t)j * 4096]);
      bb[jn] = t;
    }

    #pragma unroll
    for (int i = 0; i < 4; ++i)
      #pragma unroll
      for (int jn = 0; jn < 4; ++jn)
        acc[i][jn] = __builtin_amdgcn_mfma_f32_16x16x32_bf16(a[i], bb[jn], acc[i][jn], 0, 0, 0);
  }

  // C/D layout (HW-verified): col = lane&15 (n), row = (lane>>4)*4 + reg (m)
  #pragma unroll
  for (int i = 0; i < 4; ++i)
    #pragma unroll
    for (int jn = 0; jn < 4; ++jn)
      #pragma unroll
      for (int rr = 0; rr < 4; ++rr) {
        const int o = 64 * w + 16 * i + 4 * lg + rr;
        yb[(size_t)o * 4096 + n0 + 16 * jn + lr] = acc[i][jn][rr];
      }
}

// ---------------------------------------------------------------------------
// K4: passthrough outputs: log_det_jac (32) and z (512) appended after y.
// ---------------------------------------------------------------------------
__global__ void tail_kernel(const float* __restrict__ ldj,
                            const float* __restrict__ z,
                            float* __restrict__ out) {
  const int t = threadIdx.x;
  if (t < 32)  out[33554432u + t] = ldj[t];
  if (t < 512) out[33554464u + t] = z[t];
}

extern "C" void kernel_launch(void* const* d_in, const int* in_sizes, int n_in,
                              void* d_out, int out_size, void* d_ws, size_t ws_size,
                              hipStream_t stream) {
  const float* x   = (const float*)d_in[0];  // fp32 [32,256,64,64]
  const float* ldj = (const float*)d_in[1];  // fp32 [32]
  const float* z   = (const float*)d_in[2];  // fp32 [32,16]
  const float* V   = (const float*)d_in[3];  // fp32 [255,256]
  float* out = (float*)d_out;

  float* Vs = (float*)d_ws;                                          // 255*256 fp32
  unsigned short* Wb = (unsigned short*)((char*)d_ws + 1048576);     // 256*256 bf16

  prep_kernel<<<255, 256, 0, stream>>>(V, Vs);
  cascade_kernel<<<16, 256, 0, stream>>>(Vs, Wb);
  dim3 grid(64, 32);  // 4096/64 n-tiles x 32 batches
  conv_kernel<<<grid, 256, 0, stream>>>(x, Wb, out);
  tail_kernel<<<1, 512, 0, stream>>>(ldj, z, out);
}

// Round 3
// 154.090 us; speedup vs baseline: 1.0553x; 1.0553x over previous
//
#include <hip/hip_runtime.h>
#include <stdint.h>

typedef __attribute__((ext_vector_type(8))) short short8v;   // 8 x bf16 (4 VGPR)
typedef __attribute__((ext_vector_type(4))) float f32x4;

__device__ __forceinline__ unsigned short f2bf(float f) {
  union { float f; unsigned int i; } v; v.f = f;
  unsigned int x = v.i;
  x += 0x7FFFu + ((x >> 16) & 1u);   // round-to-nearest-even
  return (unsigned short)(x >> 16);
}

// ---------------------------------------------------------------------------
// K1: blocks 0..254: build scaled padded reflectors:
//     vfull[k][c] = (c >= 254-k) ? V[k][c] : 1.0
//     Vs[k][c]    = sqrt(2/(||vfull||^2+1e-16)) * vfull[k][c]
// block 255: passthrough tail outputs (log_det_jac, z).
// ---------------------------------------------------------------------------
__global__ void __launch_bounds__(256) prep_kernel(const float* __restrict__ V,
                                                   float* __restrict__ Vs,
                                                   const float* __restrict__ ldj,
                                                   const float* __restrict__ z,
                                                   float* __restrict__ out) {
  const int k = blockIdx.x;
  const int c = threadIdx.x;
  if (k == 255) {
    if (c < 32) out[33554432u + c] = ldj[c];
    out[33554464u + c] = z[c];
    out[33554464u + 256u + c] = z[256u + c];
    return;
  }
  float val = (c >= 254 - k) ? V[k * 256 + c] : 1.0f;
  float ss = val * val;
  #pragma unroll
  for (int off = 32; off >= 1; off >>= 1) ss += __shfl_xor(ss, off);
  __shared__ float part[4];
  if ((threadIdx.x & 63) == 0) part[threadIdx.x >> 6] = ss;
  __syncthreads();
  const float tot = part[0] + part[1] + part[2] + part[3];
  const float s = sqrtf(2.0f / (tot + 1e-16f));
  Vs[k * 256 + c] = s * val;
}

// ---------------------------------------------------------------------------
// K2: Householder cascade; Q row r evolves independently:
//     q <- q - (q . vs_k) vs_k, k = 0..254.  4 rows/wave for ILP.
// ---------------------------------------------------------------------------
__global__ void __launch_bounds__(256) cascade_kernel(const float* __restrict__ Vs,
                                                      unsigned short* __restrict__ Wb) {
  const int w = threadIdx.x >> 6;
  const int l = threadIdx.x & 63;
  const int r0 = blockIdx.x * 16 + w * 4;

  f32x4 q[4];
  #pragma unroll
  for (int j = 0; j < 4; ++j) {
    const int r = r0 + j;
    q[j][0] = (4 * l + 0 == r) ? 1.0f : 0.0f;
    q[j][1] = (4 * l + 1 == r) ? 1.0f : 0.0f;
    q[j][2] = (4 * l + 2 == r) ? 1.0f : 0.0f;
    q[j][3] = (4 * l + 3 == r) ? 1.0f : 0.0f;
  }

  const f32x4* __restrict__ Vs4 = (const f32x4*)Vs;
  f32x4 vn = Vs4[l];
  for (int k = 0; k < 255; ++k) {
    const f32x4 v = vn;
    if (k + 1 < 255) vn = Vs4[(k + 1) * 64 + l];
    float p[4];
    #pragma unroll
    for (int j = 0; j < 4; ++j)
      p[j] = q[j][0] * v[0] + q[j][1] * v[1] + q[j][2] * v[2] + q[j][3] * v[3];
    #pragma unroll
    for (int off = 32; off >= 1; off >>= 1) {
      #pragma unroll
      for (int j = 0; j < 4; ++j) p[j] += __shfl_xor(p[j], off);
    }
    #pragma unroll
    for (int j = 0; j < 4; ++j) {
      q[j][0] -= p[j] * v[0];
      q[j][1] -= p[j] * v[1];
      q[j][2] -= p[j] * v[2];
      q[j][3] -= p[j] * v[3];
    }
  }

  #pragma unroll
  for (int j = 0; j < 4; ++j) {
    ushort4 o;
    o.x = f2bf(q[j][0]); o.y = f2bf(q[j][1]); o.z = f2bf(q[j][2]); o.w = f2bf(q[j][3]);
    *(ushort4*)(Wb + (size_t)(r0 + j) * 256 + 4 * l) = o;
  }
}

// ---------------------------------------------------------------------------
// K3: y[b][o][n] = sum_c W[o][c] x[b][c][n]   (M=256, K=256, N-tile=64)
// 512 threads = 8 waves; wave w -> M rows 32w..32w+31; block covers 64 n.
// Staging: coalesced float4 global loads (2/thread/k-tile of 64), bf16 k-pair
// pack, XOR-swizzled LDS [n=64][kp=32 dw] (chunk ^= n&7): b128 reads are
// bank-conflict-free, writes 4-way (hidden). Next tile's loads issued before
// compute (T14). A-frags: 16B bf16 loads from L2-resident W.
// ---------------------------------------------------------------------------
__global__ void __launch_bounds__(512) conv_kernel(const float* __restrict__ x,
                                                   const unsigned short* __restrict__ Wb,
                                                   float* __restrict__ y) {
  __shared__ unsigned int lds[2048];   // 64 rows x 32 dwords = 8 KB

  const int b  = blockIdx.y;
  const int n0 = blockIdx.x * 64;
  const int t  = threadIdx.x;
  const int w  = t >> 6;
  const int l  = t & 63;
  const int lr = l & 15;
  const int lg = l >> 4;
  const int nq = t & 15;        // staging n-quad (n = 4nq..4nq+3)
  const int kb = t >> 4;        // staging k-pair row index 0..31 (k = 2kb, 2kb+1)

  const float* __restrict__ xb = x + (size_t)b * (256u * 4096u);
  float* __restrict__ yb = y + (size_t)b * (256u * 4096u);

  f32x4 acc[2][4];
  #pragma unroll
  for (int i = 0; i < 2; ++i)
    #pragma unroll
    for (int j = 0; j < 4; ++j)
      acc[i][j] = (f32x4){0.f, 0.f, 0.f, 0.f};

  // prologue: stage tile 0 (rows 2kb, 2kb+1)
  f32x4 r0, r1;
  {
    const f32x4* p = (const f32x4*)(xb + (size_t)(2 * kb) * 4096 + n0) + nq;
    r0 = p[0];
    r1 = p[1024];   // +4096 floats = next k-row
  }

  for (int T = 0; T < 4; ++T) {
    // pack current staged tile (waits on the global loads)
    unsigned int packed[4];
    #pragma unroll
    for (int j = 0; j < 4; ++j)
      packed[j] = (unsigned int)f2bf(r0[j]) | ((unsigned int)f2bf(r1[j]) << 16);

    if (T) __syncthreads();            // all waves done reading previous tile
    #pragma unroll
    for (int jj = 0; jj < 4; ++jj) {   // rotate write order: spreads n&7 across lanes
      const int j = (jj + nq) & 3;
      const int n = 4 * nq + j;
      const int dw = n * 32 + ((((kb >> 2) ^ (n & 7)) << 2) | (kb & 3));
      lds[dw] = packed[j];
    }
    __syncthreads();

    if (T < 3) {                       // issue next tile's loads; consumed next iter
      const f32x4* p = (const f32x4*)(xb + (size_t)(64 * (T + 1) + 2 * kb) * 4096 + n0) + nq;
      r0 = p[0];
      r1 = p[1024];
    }

    #pragma unroll
    for (int s = 0; s < 2; ++s) {      // two k-steps of 32 within the k-tile
      short8v a[2], bb[4];
      #pragma unroll
      for (int i = 0; i < 2; ++i)
        a[i] = *(const short8v*)(Wb + (size_t)(32 * w + 16 * i + lr) * 256
                                 + 64 * T + 32 * s + 8 * lg);
      #pragma unroll
      for (int jn = 0; jn < 4; ++jn) {
        const int n = 16 * jn + lr;
        const int dw = n * 32 + ((((s << 2) + lg) ^ (lr & 7)) << 2);
        bb[jn] = *(const short8v*)(&lds[dw]);
      }
      #pragma unroll
      for (int i = 0; i < 2; ++i)
        #pragma unroll
        for (int jn = 0; jn < 4; ++jn)
          acc[i][jn] = __builtin_amdgcn_mfma_f32_16x16x32_bf16(a[i], bb[jn], acc[i][jn], 0, 0, 0);
    }
  }

  // C/D layout (HW-verified): col = lane&15 (n), row = (lane>>4)*4 + reg (m)
  #pragma unroll
  for (int i = 0; i < 2; ++i)
    #pragma unroll
    for (int jn = 0; jn < 4; ++jn)
      #pragma unroll
      for (int rr = 0; rr < 4; ++rr) {
        const int o = 32 * w + 16 * i + 4 * lg + rr;
        yb[(size_t)o * 4096 + n0 + 16 * jn + lr] = acc[i][jn][rr];
      }
}

extern "C" void kernel_launch(void* const* d_in, const int* in_sizes, int n_in,
                              void* d_out, int out_size, void* d_ws, size_t ws_size,
                              hipStream_t stream) {
  const float* x   = (const float*)d_in[0];  // fp32 [32,256,64,64]
  const float* ldj = (const float*)d_in[1];  // fp32 [32]
  const float* z   = (const float*)d_in[2];  // fp32 [32,16]
  const float* V   = (const float*)d_in[3];  // fp32 [255,256]
  float* out = (float*)d_out;

  float* Vs = (float*)d_ws;                                          // 255*256 fp32
  unsigned short* Wb = (unsigned short*)((char*)d_ws + 1048576);     // 256*256 bf16

  prep_kernel<<<256, 256, 0, stream>>>(V, Vs, ldj, z, out);
  cascade_kernel<<<16, 256, 0, stream>>>(Vs, Wb);
  dim3 grid(64, 32);
  conv_kernel<<<grid, 512, 0, stream>>>(x, Wb, out);
}